// Round 1
// baseline (2620.310 us; speedup 1.0000x reference)
//
#include <hip/hip_runtime.h>
#include <math.h>
#include <stdint.h>

// Shapes (fixed by the reference)
// N=10000, E=100000, G=64, NB=16, EMB=16, S=8, COUT=16, LMAX=2
// WNUM = 3*16*8*8 = 3072 ; ef width = 16 + 48 + 144 = 208
// Per-edge compact result: m[48] (l*16+o) + n[3], stored as 52 floats.

__device__ __forceinline__ float silu_f(float x) {
    return x / (1.0f + __expf(-x));
}

// ---------------- kernel 1: transpose fc_w3 (64 x 3072) -> w3T[lo][ab][c] ----------------
__global__ __launch_bounds__(256) void k_transpose_w3(const float* __restrict__ w3,
                                                      float* __restrict__ w3T) {
    int t = blockIdx.x * 256 + threadIdx.x;       // t = lo*4096 + ab*64 + c
    if (t >= 48 * 64 * 64) return;
    int c  = t & 63;
    int ab = (t >> 6) & 63;
    int lo = t >> 12;
    w3T[t] = w3[c * 3072 + lo * 64 + ab];
}

// ---------------- kernel 2: per-node Ai = silu(emb_table[A] @ mlp_w1 + b1) @ mlp_w2 + b2 ----------------
__global__ __launch_bounds__(256) void k_node_ai(const int* __restrict__ A,
                                                 const float* __restrict__ embt,
                                                 const float* __restrict__ w1,
                                                 const float* __restrict__ b1,
                                                 const float* __restrict__ w2,
                                                 const float* __restrict__ b2,
                                                 float* __restrict__ Ai, int N) {
    int i = blockIdx.x * 256 + threadIdx.x;
    if (i >= N) return;
    float e[16];
    const float* er = embt + A[i] * 16;
    #pragma unroll
    for (int k = 0; k < 16; ++k) e[k] = er[k];
    float h1[64];
    #pragma unroll
    for (int j = 0; j < 64; ++j) {
        float a = b1[j];
        #pragma unroll
        for (int k = 0; k < 16; ++k) a = fmaf(e[k], w1[k * 64 + j], a);
        h1[j] = silu_f(a);
    }
    #pragma unroll
    for (int o = 0; o < 8; ++o) {
        float a = b2[o];
        #pragma unroll
        for (int j = 0; j < 64; ++j) a = fmaf(h1[j], w2[j * 8 + o], a);
        Ai[i * 8 + o] = a;
    }
}

// ---------------- kernel 3: histogram of edge_dst ----------------
__global__ __launch_bounds__(256) void k_hist(const int* __restrict__ edst,
                                              int* __restrict__ deg, int E) {
    int e = blockIdx.x * 256 + threadIdx.x;
    if (e < E) atomicAdd(&deg[edst[e]], 1);
}

// ---------------- kernel 4: single-block exclusive scan (N=10000) ----------------
__global__ __launch_bounds__(256) void k_scan(const int* __restrict__ deg,
                                              int* __restrict__ offs,
                                              int* __restrict__ cursor, int N) {
    __shared__ int part[256];
    const int t = threadIdx.x;
    const int chunk = (N + 255) / 256;
    const int beg = t * chunk;
    const int end = min(beg + chunk, N);
    int s = 0;
    for (int i = beg; i < end; ++i) s += deg[i];
    part[t] = s;
    __syncthreads();
    // Hillis-Steele inclusive scan over 256 partials
    for (int off = 1; off < 256; off <<= 1) {
        int v = (t >= off) ? part[t - off] : 0;
        __syncthreads();
        part[t] += v;
        __syncthreads();
    }
    int run = (t == 0) ? 0 : part[t - 1];   // exclusive prefix of this chunk
    for (int i = beg; i < end; ++i) {
        offs[i] = run;
        cursor[i] = run;
        run += deg[i];
    }
    if (t == 255) offs[N] = part[255];
}

// ---------------- kernel 5: per-edge compute (no float atomics) ----------------
// Block = 256 threads = 4 waves. Each wave handles the SAME 64 edges but a
// disjoint quarter of the 48 lo-outputs (wave-uniform lo -> scalar weight loads).
// Writes m[48]+n[3] per edge to ef; wave 0 also scatters the edge id into the
// CSR index (int atomic on cursor).
__global__ __launch_bounds__(256) void k_edge(
    const float* __restrict__ pos, const int* __restrict__ batch,
    const int* __restrict__ esrc, const int* __restrict__ edst,
    const float* __restrict__ eshift, const float* __restrict__ cell,
    const float* __restrict__ fw1, const float* __restrict__ fb1,
    const float* __restrict__ fw2, const float* __restrict__ fb2,
    const float* __restrict__ w3T, const float* __restrict__ b3,
    const float* __restrict__ Ai, float* __restrict__ ef,
    int* __restrict__ cursor, int* __restrict__ eidx, int E) {

    __shared__ float s_fs[4 * 64 * 9];   // stride 9 -> bank-conflict-free runtime indexing
    __shared__ float s_fd[4 * 64 * 9];

    const int tid  = threadIdx.x;
    const int lane = tid & 63;
    const int wq   = tid >> 6;                 // 0..3 : lo-quarter (wave-uniform)
    const int e    = blockIdx.x * 64 + lane;
    if (e >= E) return;

    const int src = esrc[e];
    const int dst = edst[e];

    // ---- geometry ----
    const int g = batch[src];
    const float s0 = eshift[e * 3 + 0], s1 = eshift[e * 3 + 1], s2 = eshift[e * 3 + 2];
    const float* cl = cell + g * 9;
    float vx = pos[dst * 3 + 0] - pos[src * 3 + 0] + s0 * cl[0] + s1 * cl[3] + s2 * cl[6];
    float vy = pos[dst * 3 + 1] - pos[src * 3 + 1] + s0 * cl[1] + s1 * cl[4] + s2 * cl[7];
    float vz = pos[dst * 3 + 2] - pos[src * 3 + 2] + s0 * cl[2] + s1 * cl[5] + s2 * cl[8];
    float r = sqrtf(vx * vx + vy * vy + vz * vz);
    float rinv = 1.0f / fmaxf(r, 1e-9f);
    float nx = vx * rinv, ny = vy * rinv, nz = vz * rinv;

    // ---- radial basis (NB=16) ----
    float emb[16];
    const float step = 4.0f / 17.0f;
    const float sc = 4.0f / 1.12f;      // sqrt(16)/1.12
    #pragma unroll
    for (int k = 0; k < 16; ++k) {
        float d = (r - (float)(k + 1) * step) / step;
        emb[k] = __expf(-d * d) * sc;
    }

    // ---- h1 = silu(emb @ fc_w1 + fb1) ----
    float h1[64];
    #pragma unroll
    for (int j = 0; j < 64; ++j) {
        float a = fb1[j];
        #pragma unroll
        for (int k = 0; k < 16; ++k) a = fmaf(emb[k], fw1[k * 64 + j], a);
        h1[j] = silu_f(a);
    }

    // ---- h = silu(h1 @ fc_w2 + fb2) ----
    float h[64];
    #pragma unroll
    for (int c = 0; c < 64; ++c) {
        float a = fb2[c];
        #pragma unroll
        for (int j = 0; j < 64; ++j) a = fmaf(h1[j], fw2[j * 64 + c], a);
        h[c] = silu_f(a);
    }

    // ---- fs, fd to LDS (padded, private per thread, runtime-indexable) ----
    const int t9 = (wq * 64 + lane) * 9;
    #pragma unroll
    for (int a = 0; a < 8; ++a) {
        s_fs[t9 + a] = Ai[src * 8 + a];
        s_fd[t9 + a] = Ai[dst * 8 + a];
    }

    float* mp = ef + (size_t)e * 52;

    // ---- main contraction: m[lo] = sum_ab (b3 + sum_c h[c] w3T[lo][ab][c]) * fs[a] fd[b] ----
    const int lo0 = wq * 12;
    for (int lo = lo0; lo < lo0 + 12; ++lo) {
        const float* wb = w3T + lo * 4096;
        const float* bb = b3 + lo * 64;
        float macc = 0.0f;
        for (int ab = 0; ab < 64; ++ab) {
            const float* wr = wb + ab * 64;
            float a0 = 0.f, a1 = 0.f, a2 = 0.f, a3 = 0.f;
            #pragma unroll
            for (int c = 0; c < 64; c += 4) {
                a0 = fmaf(h[c + 0], wr[c + 0], a0);
                a1 = fmaf(h[c + 1], wr[c + 1], a1);
                a2 = fmaf(h[c + 2], wr[c + 2], a2);
                a3 = fmaf(h[c + 3], wr[c + 3], a3);
            }
            float Wv = ((a0 + a1) + (a2 + a3)) + bb[ab];
            macc = fmaf(Wv * s_fs[t9 + (ab >> 3)], s_fd[t9 + (ab & 7)], macc);
        }
        mp[lo] = macc;
    }

    if (wq == 0) {
        mp[48] = nx; mp[49] = ny; mp[50] = nz;
        int p = atomicAdd(&cursor[dst], 1);
        eidx[p] = e;
    }
}

// ---------------- kernel 6: gather-reduce per node ----------------
// One wave per node. Lane l owns output components {l, l+64, l+128, l+192(<208)}.
// Per incident edge: one coalesced 52-float read, redistribute via shuffles.
__global__ __launch_bounds__(256) void k_gather(const float* __restrict__ ef,
                                                const int* __restrict__ offs,
                                                const int* __restrict__ eidx,
                                                float* __restrict__ out, int N) {
    const int lane = threadIdx.x & 63;
    const int node = blockIdx.x * 4 + (threadIdx.x >> 6);
    if (node >= N) return;

    const int beg = offs[node];
    const int end = offs[node + 1];

    // component mapping: c<16 -> m[c]; 16<=c<64 -> m[16+o]*n[i]; 64<=c<208 -> m[32+o]*n[i]*n[j]
    int mi[4], ii[4], jj[4], mode[4];
    #pragma unroll
    for (int t = 0; t < 4; ++t) {
        int c = lane + 64 * t;
        if (c < 16)       { mi[t] = c;                 ii[t] = 0;     jj[t] = 0;     mode[t] = 0; }
        else if (c < 64)  { int u = c - 16; mi[t] = 16 + u / 3; ii[t] = u % 3; jj[t] = 0; mode[t] = 1; }
        else if (c < 208) { int u = c - 64; mi[t] = 32 + u / 9; int rr = u % 9; ii[t] = rr / 3; jj[t] = rr % 3; mode[t] = 2; }
        else              { mi[t] = 0; ii[t] = 0; jj[t] = 0; mode[t] = 3; }
    }

    float acc[4] = {0.f, 0.f, 0.f, 0.f};
    for (int k = beg; k < end; ++k) {
        const int e = eidx[k];
        const float* b = ef + (size_t)e * 52;
        float v = (lane < 51) ? b[lane] : 0.0f;     // coalesced: m[0..47], n[48..50]
        float n0 = __shfl(v, 48);
        float n1 = __shfl(v, 49);
        float n2 = __shfl(v, 50);
        #pragma unroll
        for (int t = 0; t < 4; ++t) {
            float mval = __shfl(v, mi[t]);
            float ni = (ii[t] == 0) ? n0 : ((ii[t] == 1) ? n1 : n2);
            float nj = (jj[t] == 0) ? n0 : ((jj[t] == 1) ? n1 : n2);
            float f  = (mode[t] == 0) ? 1.0f
                     : (mode[t] == 1) ? ni
                     : (mode[t] == 2) ? ni * nj
                     : 0.0f;
            acc[t] = fmaf(mval, f, acc[t]);
        }
    }

    const float inv = 1.0f / fmaxf((float)(end - beg), 1.0f);
    float* op = out + (size_t)node * 208;
    op[lane]        = acc[0] * inv;
    op[lane + 64]   = acc[1] * inv;
    op[lane + 128]  = acc[2] * inv;
    if (lane < 16) op[lane + 192] = acc[3] * inv;
}

extern "C" void kernel_launch(void* const* d_in, const int* in_sizes, int n_in,
                              void* d_out, int out_size, void* d_ws, size_t ws_size,
                              hipStream_t stream) {
    const float* pos    = (const float*)d_in[0];
    const int*   A      = (const int*)d_in[1];
    const int*   batch  = (const int*)d_in[2];
    const int*   esrc   = (const int*)d_in[3];
    const int*   edst   = (const int*)d_in[4];
    const float* eshift = (const float*)d_in[5];
    const float* cell   = (const float*)d_in[6];
    const float* embt   = (const float*)d_in[7];
    const float* mw1    = (const float*)d_in[8];
    const float* mb1    = (const float*)d_in[9];
    const float* mw2    = (const float*)d_in[10];
    const float* mb2    = (const float*)d_in[11];
    const float* fw1    = (const float*)d_in[12];
    const float* fb1    = (const float*)d_in[13];
    const float* fw2    = (const float*)d_in[14];
    const float* fb2    = (const float*)d_in[15];
    const float* w3     = (const float*)d_in[16];
    const float* b3     = (const float*)d_in[17];
    float* out = (float*)d_out;

    const int N = in_sizes[1];
    const int E = in_sizes[3];

    char* p = (char*)d_ws;
    auto take = [&](size_t bytes) {
        char* q = p;
        p += (bytes + 255) & ~(size_t)255;
        return q;
    };
    float* w3T    = (float*)take(48 * 64 * 64 * sizeof(float));   // 768 KiB
    float* Ai     = (float*)take((size_t)N * 8 * sizeof(float));
    int*   deg    = (int*)  take((size_t)N * sizeof(int));
    int*   offs   = (int*)  take((size_t)(N + 1) * sizeof(int));
    int*   cursor = (int*)  take((size_t)N * sizeof(int));
    int*   eidx   = (int*)  take((size_t)E * sizeof(int));
    float* ef     = (float*)take((size_t)E * 52 * sizeof(float)); // ~20.8 MiB

    hipMemsetAsync(deg, 0, (size_t)N * sizeof(int), stream);

    k_transpose_w3<<<(48 * 64 * 64 + 255) / 256, 256, 0, stream>>>(w3, w3T);
    k_node_ai<<<(N + 255) / 256, 256, 0, stream>>>(A, embt, mw1, mb1, mw2, mb2, Ai, N);
    k_hist<<<(E + 255) / 256, 256, 0, stream>>>(edst, deg, E);
    k_scan<<<1, 256, 0, stream>>>(deg, offs, cursor, N);
    k_edge<<<(E + 63) / 64, 256, 0, stream>>>(pos, batch, esrc, edst, eshift, cell,
                                              fw1, fb1, fw2, fb2, w3T, b3, Ai,
                                              ef, cursor, eidx, E);
    k_gather<<<(N + 3) / 4, 256, 0, stream>>>(ef, offs, eidx, out, N);
}

// Round 2
// 997.587 us; speedup vs baseline: 2.6266x; 2.6266x over previous
//
#include <hip/hip_runtime.h>
#include <math.h>
#include <stdint.h>

// Shapes (fixed by the reference)
// N=10000, E=100000, G=64, NB=16, EMB=16, S=8, COUT=16, LMAX=2
// WNUM = 3*16*8*8 = 3072 ; ef width = 16 + 48 + 144 = 208
// Per-edge compact result: m[48] (l*16+o) + n[3], stored as 52 floats.

__device__ __forceinline__ float silu_f(float x) {
    return x / (1.0f + __expf(-x));
}

// ---------------- kernel 1: transpose fc_w3 (64 x 3072) -> w3T[lo][ab][c] ----------------
__global__ __launch_bounds__(256) void k_transpose_w3(const float* __restrict__ w3,
                                                      float* __restrict__ w3T) {
    int t = blockIdx.x * 256 + threadIdx.x;       // t = lo*4096 + ab*64 + c
    if (t >= 48 * 64 * 64) return;
    int c  = t & 63;
    int ab = (t >> 6) & 63;
    int lo = t >> 12;
    w3T[t] = w3[c * 3072 + lo * 64 + ab];
}

// ---------------- kernel 2: per-node Ai = silu(emb_table[A] @ mlp_w1 + b1) @ mlp_w2 + b2 ----------------
// launch_bounds(256,2): keep h1[64] in registers (no scratch spill).
__global__ __launch_bounds__(256, 2) void k_node_ai(const int* __restrict__ A,
                                                    const float* __restrict__ embt,
                                                    const float* __restrict__ w1,
                                                    const float* __restrict__ b1,
                                                    const float* __restrict__ w2,
                                                    const float* __restrict__ b2,
                                                    float* __restrict__ Ai, int N) {
    int i = blockIdx.x * 256 + threadIdx.x;
    if (i >= N) return;
    float e[16];
    const float* er = embt + A[i] * 16;
    #pragma unroll
    for (int k = 0; k < 16; ++k) e[k] = er[k];
    float h1[64];
    #pragma unroll
    for (int j = 0; j < 64; ++j) {
        float a = b1[j];
        #pragma unroll
        for (int k = 0; k < 16; ++k) a = fmaf(e[k], w1[k * 64 + j], a);
        h1[j] = silu_f(a);
    }
    #pragma unroll
    for (int o = 0; o < 8; ++o) {
        float a = b2[o];
        #pragma unroll
        for (int j = 0; j < 64; ++j) a = fmaf(h1[j], w2[j * 8 + o], a);
        Ai[i * 8 + o] = a;
    }
}

// ---------------- kernel 3: histogram of edge_dst ----------------
__global__ __launch_bounds__(256) void k_hist(const int* __restrict__ edst,
                                              int* __restrict__ deg, int E) {
    int e = blockIdx.x * 256 + threadIdx.x;
    if (e < E) atomicAdd(&deg[edst[e]], 1);
}

// ---------------- kernel 4: single-block exclusive scan (N=10000) ----------------
__global__ __launch_bounds__(256) void k_scan(const int* __restrict__ deg,
                                              int* __restrict__ offs,
                                              int* __restrict__ cursor, int N) {
    __shared__ int part[256];
    const int t = threadIdx.x;
    const int chunk = (N + 255) / 256;
    const int beg = t * chunk;
    const int end = min(beg + chunk, N);
    int s = 0;
    for (int i = beg; i < end; ++i) s += deg[i];
    part[t] = s;
    __syncthreads();
    // Hillis-Steele inclusive scan over 256 partials
    for (int off = 1; off < 256; off <<= 1) {
        int v = (t >= off) ? part[t - off] : 0;
        __syncthreads();
        part[t] += v;
        __syncthreads();
    }
    int run = (t == 0) ? 0 : part[t - 1];   // exclusive prefix of this chunk
    for (int i = beg; i < end; ++i) {
        offs[i] = run;
        cursor[i] = run;
        run += deg[i];
    }
    if (t == 255) offs[N] = part[255];
}

// ---------------- kernel 5: per-edge compute (no float atomics) ----------------
// Block = 256 threads = 4 waves. Each wave handles the SAME 64 edges but a
// disjoint quarter of the 48 lo-outputs. wq forced into an SGPR via
// readfirstlane so the w3T/b3 streams stay on the scalar pipe.
// launch_bounds(256,2): VGPR budget 256 so h1[64]+h[64] live in registers.
__global__ __launch_bounds__(256, 2) void k_edge(
    const float* __restrict__ pos, const int* __restrict__ batch,
    const int* __restrict__ esrc, const int* __restrict__ edst,
    const float* __restrict__ eshift, const float* __restrict__ cell,
    const float* __restrict__ fw1, const float* __restrict__ fb1,
    const float* __restrict__ fw2, const float* __restrict__ fb2,
    const float* __restrict__ w3T, const float* __restrict__ b3,
    const float* __restrict__ Ai, float* __restrict__ ef,
    int* __restrict__ cursor, int* __restrict__ eidx, int E) {

    __shared__ float s_fs[4 * 64 * 9];   // stride 9 -> bank-conflict-free runtime indexing
    __shared__ float s_fd[4 * 64 * 9];

    const int tid  = threadIdx.x;
    const int lane = tid & 63;
    // wave-uniform lo-quarter, forced into SGPR (compiler can't prove tid>>6 uniform)
    const int wq   = __builtin_amdgcn_readfirstlane(tid >> 6);
    const int e    = blockIdx.x * 64 + lane;
    if (e >= E) return;

    const int src = esrc[e];
    const int dst = edst[e];

    // ---- geometry ----
    const int g = batch[src];
    const float s0 = eshift[e * 3 + 0], s1 = eshift[e * 3 + 1], s2 = eshift[e * 3 + 2];
    const float* cl = cell + g * 9;
    float vx = pos[dst * 3 + 0] - pos[src * 3 + 0] + s0 * cl[0] + s1 * cl[3] + s2 * cl[6];
    float vy = pos[dst * 3 + 1] - pos[src * 3 + 1] + s0 * cl[1] + s1 * cl[4] + s2 * cl[7];
    float vz = pos[dst * 3 + 2] - pos[src * 3 + 2] + s0 * cl[2] + s1 * cl[5] + s2 * cl[8];
    float r = sqrtf(vx * vx + vy * vy + vz * vz);
    float rinv = 1.0f / fmaxf(r, 1e-9f);
    float nx = vx * rinv, ny = vy * rinv, nz = vz * rinv;

    // ---- radial basis (NB=16) ----
    float emb[16];
    const float step = 4.0f / 17.0f;
    const float sc = 4.0f / 1.12f;      // sqrt(16)/1.12
    #pragma unroll
    for (int k = 0; k < 16; ++k) {
        float d = (r - (float)(k + 1) * step) / step;
        emb[k] = __expf(-d * d) * sc;
    }

    // ---- h1 = silu(emb @ fc_w1 + fb1) ----
    float h1[64];
    #pragma unroll
    for (int j = 0; j < 64; ++j) {
        float a = fb1[j];
        #pragma unroll
        for (int k = 0; k < 16; ++k) a = fmaf(emb[k], fw1[k * 64 + j], a);
        h1[j] = silu_f(a);
    }

    // ---- h = silu(h1 @ fc_w2 + fb2) ----
    float h[64];
    #pragma unroll
    for (int c = 0; c < 64; ++c) {
        float a = fb2[c];
        #pragma unroll
        for (int j = 0; j < 64; ++j) a = fmaf(h1[j], fw2[j * 64 + c], a);
        h[c] = silu_f(a);
    }

    // ---- fs, fd to LDS (padded, private per thread, runtime-indexable) ----
    const int t9 = (wq * 64 + lane) * 9;
    #pragma unroll
    for (int a = 0; a < 8; ++a) {
        s_fs[t9 + a] = Ai[src * 8 + a];
        s_fd[t9 + a] = Ai[dst * 8 + a];
    }

    // ---- main contraction: m[lo] = sum_ab (b3 + sum_c h[c] w3T[lo][ab][c]) * fs[a] fd[b] ----
    const int lo0 = wq * 12;
    float m12[12];
    #pragma unroll
    for (int q = 0; q < 12; ++q) {
        const int lo = lo0 + q;
        const float* wb = w3T + lo * 4096;   // uniform (SGPR) base -> scalar loads
        const float* bb = b3 + lo * 64;
        float macc = 0.0f;
        for (int ab = 0; ab < 64; ++ab) {
            const float* wr = wb + ab * 64;
            float a0 = 0.f, a1 = 0.f, a2 = 0.f, a3 = 0.f;
            #pragma unroll
            for (int c = 0; c < 64; c += 4) {
                a0 = fmaf(h[c + 0], wr[c + 0], a0);
                a1 = fmaf(h[c + 1], wr[c + 1], a1);
                a2 = fmaf(h[c + 2], wr[c + 2], a2);
                a3 = fmaf(h[c + 3], wr[c + 3], a3);
            }
            float Wv = ((a0 + a1) + (a2 + a3)) + bb[ab];
            macc = fmaf(Wv * s_fs[t9 + (ab >> 3)], s_fd[t9 + (ab & 7)], macc);
        }
        m12[q] = macc;
    }

    // ---- store: 3 x float4 (ef base + e*52 + wq*12 is 16B-aligned) ----
    float* mp = ef + (size_t)e * 52 + lo0;
    #pragma unroll
    for (int q = 0; q < 3; ++q) {
        float4 v = make_float4(m12[q * 4 + 0], m12[q * 4 + 1], m12[q * 4 + 2], m12[q * 4 + 3]);
        *reinterpret_cast<float4*>(mp + q * 4) = v;
    }

    if (wq == 0) {
        float* np = ef + (size_t)e * 52;
        np[48] = nx; np[49] = ny; np[50] = nz;
        int p = atomicAdd(&cursor[dst], 1);
        eidx[p] = e;
    }
}

// ---------------- kernel 6: gather-reduce per node ----------------
// One wave per node. Lane l owns output components {l, l+64, l+128, l+192(<208)}.
// Per incident edge: one coalesced 52-float read, redistribute via shuffles.
__global__ __launch_bounds__(256) void k_gather(const float* __restrict__ ef,
                                                const int* __restrict__ offs,
                                                const int* __restrict__ eidx,
                                                float* __restrict__ out, int N) {
    const int lane = threadIdx.x & 63;
    const int node = blockIdx.x * 4 + (threadIdx.x >> 6);
    if (node >= N) return;

    const int beg = offs[node];
    const int end = offs[node + 1];

    // component mapping: c<16 -> m[c]; 16<=c<64 -> m[16+o]*n[i]; 64<=c<208 -> m[32+o]*n[i]*n[j]
    int mi[4], ii[4], jj[4], mode[4];
    #pragma unroll
    for (int t = 0; t < 4; ++t) {
        int c = lane + 64 * t;
        if (c < 16)       { mi[t] = c;                 ii[t] = 0;     jj[t] = 0;     mode[t] = 0; }
        else if (c < 64)  { int u = c - 16; mi[t] = 16 + u / 3; ii[t] = u % 3; jj[t] = 0; mode[t] = 1; }
        else if (c < 208) { int u = c - 64; mi[t] = 32 + u / 9; int rr = u % 9; ii[t] = rr / 3; jj[t] = rr % 3; mode[t] = 2; }
        else              { mi[t] = 0; ii[t] = 0; jj[t] = 0; mode[t] = 3; }
    }

    float acc[4] = {0.f, 0.f, 0.f, 0.f};
    for (int k = beg; k < end; ++k) {
        const int e = eidx[k];
        const float* b = ef + (size_t)e * 52;
        float v = (lane < 51) ? b[lane] : 0.0f;     // coalesced: m[0..47], n[48..50]
        float n0 = __shfl(v, 48);
        float n1 = __shfl(v, 49);
        float n2 = __shfl(v, 50);
        #pragma unroll
        for (int t = 0; t < 4; ++t) {
            float mval = __shfl(v, mi[t]);
            float ni = (ii[t] == 0) ? n0 : ((ii[t] == 1) ? n1 : n2);
            float nj = (jj[t] == 0) ? n0 : ((jj[t] == 1) ? n1 : n2);
            float f  = (mode[t] == 0) ? 1.0f
                     : (mode[t] == 1) ? ni
                     : (mode[t] == 2) ? ni * nj
                     : 0.0f;
            acc[t] = fmaf(mval, f, acc[t]);
        }
    }

    const float inv = 1.0f / fmaxf((float)(end - beg), 1.0f);
    float* op = out + (size_t)node * 208;
    op[lane]        = acc[0] * inv;
    op[lane + 64]   = acc[1] * inv;
    op[lane + 128]  = acc[2] * inv;
    if (lane < 16) op[lane + 192] = acc[3] * inv;
}

extern "C" void kernel_launch(void* const* d_in, const int* in_sizes, int n_in,
                              void* d_out, int out_size, void* d_ws, size_t ws_size,
                              hipStream_t stream) {
    const float* pos    = (const float*)d_in[0];
    const int*   A      = (const int*)d_in[1];
    const int*   batch  = (const int*)d_in[2];
    const int*   esrc   = (const int*)d_in[3];
    const int*   edst   = (const int*)d_in[4];
    const float* eshift = (const float*)d_in[5];
    const float* cell   = (const float*)d_in[6];
    const float* embt   = (const float*)d_in[7];
    const float* mw1    = (const float*)d_in[8];
    const float* mb1    = (const float*)d_in[9];
    const float* mw2    = (const float*)d_in[10];
    const float* mb2    = (const float*)d_in[11];
    const float* fw1    = (const float*)d_in[12];
    const float* fb1    = (const float*)d_in[13];
    const float* fw2    = (const float*)d_in[14];
    const float* fb2    = (const float*)d_in[15];
    const float* w3     = (const float*)d_in[16];
    const float* b3     = (const float*)d_in[17];
    float* out = (float*)d_out;

    const int N = in_sizes[1];
    const int E = in_sizes[3];

    char* p = (char*)d_ws;
    auto take = [&](size_t bytes) {
        char* q = p;
        p += (bytes + 255) & ~(size_t)255;
        return q;
    };
    float* w3T    = (float*)take(48 * 64 * 64 * sizeof(float));   // 768 KiB
    float* Ai     = (float*)take((size_t)N * 8 * sizeof(float));
    int*   deg    = (int*)  take((size_t)N * sizeof(int));
    int*   offs   = (int*)  take((size_t)(N + 1) * sizeof(int));
    int*   cursor = (int*)  take((size_t)N * sizeof(int));
    int*   eidx   = (int*)  take((size_t)E * sizeof(int));
    float* ef     = (float*)take((size_t)E * 52 * sizeof(float)); // ~20.8 MiB

    hipMemsetAsync(deg, 0, (size_t)N * sizeof(int), stream);

    k_transpose_w3<<<(48 * 64 * 64 + 255) / 256, 256, 0, stream>>>(w3, w3T);
    k_node_ai<<<(N + 255) / 256, 256, 0, stream>>>(A, embt, mw1, mb1, mw2, mb2, Ai, N);
    k_hist<<<(E + 255) / 256, 256, 0, stream>>>(edst, deg, E);
    k_scan<<<1, 256, 0, stream>>>(deg, offs, cursor, N);
    k_edge<<<(E + 63) / 64, 256, 0, stream>>>(pos, batch, esrc, edst, eshift, cell,
                                              fw1, fb1, fw2, fb2, w3T, b3, Ai,
                                              ef, cursor, eidx, E);
    k_gather<<<(N + 3) / 4, 256, 0, stream>>>(ef, offs, eidx, out, N);
}